// Round 13
// baseline (342.615 us; speedup 1.0000x reference)
//
#include <hip/hip_runtime.h>

#define NND   8192
#define DDIM  256
#define NGRP  32
#define ZEROF 1e-8f
#define LSTR  40   // K-loop LDS row stride in u16
#define TSTR  72   // epilogue transpose tile stride in u16
// flat LDS layout (u16 units). TT aliases B-staging (dead after K-loop).
#define OFF_AH 0
#define OFF_AL 2560
#define OFF_BH 5120
#define OFF_BL 10240
#define OFF_TT 5120
#define LDS_U16 15360

typedef unsigned short u16;
typedef __attribute__((ext_vector_type(8))) short short8v;
typedef __attribute__((ext_vector_type(4))) float float4v;

__device__ inline u16 f2bf(float x) {
  unsigned u = __float_as_uint(x);
  u += 0x7fffu + ((u >> 16) & 1u);
  return (u16)(u >> 16);
}
__device__ inline float bf2f(u16 h) { return __uint_as_float((unsigned)h << 16); }
__device__ inline void split2(float x, u16& h, u16& l) {
  h = f2bf(x);
  l = f2bf(x - bf2f(h));
}

__device__ inline float wave_sum(float v) {
#pragma unroll
  for (int off = 32; off > 0; off >>= 1) v += __shfl_down(v, off, 64);
  return v;
}

// ================= unified split-bf16 MFMA GEMM body =================
// C-tile 64 x (HALF?64:128), 4 waves, 16x16x32 bf16 MFMA, split-bf16x3.
// MODE 0: XWT[c][node] = (H @ Wcat)^T      a=H(node), b=Wt(c)        [full]
// MODE 1: Hout = relu(b3 + M @ XWcat)      a=XWT(d), b=M fp32, K=768 [half]
//         STRIDED: B from interleaved MC (value at even float index)
// MODE 2: A = (x.xT)*di*dj/(ni*nj+eps)     a=b=x                     [half]
// MODE 3: A = 0.5A + 0.5 sigmoid(t.HT)     a=tmp, b=H                [half]
//         if Ch!=null: also M1[g,t][col][row] = MC[...].cnt * A_new[row][col]
// MODE 4: tmp[node][d] = H @ T             a=Tt(d), b=H(node)        [half]
#define LOAD_REGS(tt, kk)                                                                   \
  {                                                                                         \
    int m_ = tid >> 2, kq_ = (tid & 3) * 8;                                                 \
    size_t aoff_;                                                                           \
    if (MODE == 1)                                                                          \
      aoff_ = (size_t)((tt) * 256 + bym * 64 + m_) * 8192 + (size_t)(g * 256 + (kk) + kq_); \
    else if (MODE == 2 || MODE == 3)                                                        \
      aoff_ = (size_t)(g * 256 + bym * 64 + m_) * 256 + (kk) + kq_;                         \
    else                                                                                    \
      aoff_ = (size_t)(bym * 64 + m_) * 256 + (kk) + kq_;                                   \
    rAh = *(const short8v*)&Ah_g[aoff_];                                                    \
    rAl = *(const short8v*)&Al_g[aoff_];                                                    \
    if (MODE == 1) {                                                                        \
      int n_ = tid >> 2, kq2_ = (tid & 3) * 8;                                              \
      size_t cb_ = (((size_t)g * 3 + (tt)) << 16) + (size_t)(col0 + n_) * 256 + (kk) + kq2_;\
      if (STRIDED) {                                                                        \
        const float* pb_ = Bfp + cb_ * 2;                                                   \
        rBf[0] = *(const float4*)pb_;        rBf[1] = *(const float4*)(pb_ + 4);            \
        rBf[2] = *(const float4*)(pb_ + 8);  rBf[3] = *(const float4*)(pb_ + 12);           \
      } else {                                                                              \
        const float* pb_ = Bfp + cb_;                                                       \
        rBf[0] = *(const float4*)pb_;        rBf[1] = *(const float4*)(pb_ + 4);            \
      }                                                                                     \
    } else if (HALF) {                                                                      \
      int n_ = tid & 63, kq2_ = (tid >> 6) * 8;                                             \
      size_t boff_ = (size_t)(((MODE == 2 || MODE == 3) ? g * 256 : 0) + col0 + n_) * 256   \
                     + (kk) + kq2_;                                                         \
      rBh0 = *(const short8v*)&Bh_g[boff_];                                                 \
      rBl0 = *(const short8v*)&Bl_g[boff_];                                                 \
    } else {                                                                                \
      int n_ = tid & 127, kq2_ = (tid >> 7) * 16;                                           \
      size_t boff_ = (size_t)(col0 + n_) * 256 + (kk) + kq2_;                               \
      rBh0 = *(const short8v*)&Bh_g[boff_]; rBh1 = *(const short8v*)&Bh_g[boff_ + 8];       \
      rBl0 = *(const short8v*)&Bl_g[boff_]; rBl1 = *(const short8v*)&Bl_g[boff_ + 8];       \
    }                                                                                       \
  }

template<int MODE, bool HALF, bool STRIDED = false>
__device__ __forceinline__ void mfma_body(
    u16* lds,
    const u16* __restrict__ Ah_g, const u16* __restrict__ Al_g,
    const u16* __restrict__ Bh_g, const u16* __restrict__ Bl_g,
    const float* __restrict__ Bfp,          // MODE1: M source; MODE3: MC (for M1 build)
    float* __restrict__ Cf, u16* __restrict__ Ch, u16* __restrict__ Cl,
    const float* __restrict__ nrm, const float* __restrict__ dinv,
    const float* __restrict__ bias,
    int bxm, int bym, int g) {
  u16* Ahs = lds + OFF_AH;
  u16* Als = lds + OFF_AL;
  u16* Bhs = lds + OFF_BH;
  u16* Bls = lds + OFF_BL;
  u16* Tt  = lds + OFF_TT;
  const int NJ = HALF ? 2 : 4;
  const int tid = threadIdx.x;
  const int col0 = bxm * (HALF ? 64 : 128);
  const int w = tid >> 6, lane = tid & 63;
  const int lm = lane & 15, lq = lane >> 4;
  const int wr = (w >> 1) * 32, wc = (w & 1) * (HALF ? 32 : 64);

  float4v acc[2][4];
#pragma unroll
  for (int i = 0; i < 2; ++i)
#pragma unroll
    for (int j = 0; j < NJ; ++j) acc[i][j] = (float4v)0.f;

  short8v rAh, rAl, rBh0, rBh1, rBl0, rBl1;
  float4 rBf[4];
  const int TOTAL = (MODE == 1) ? 24 : 8;

  LOAD_REGS(0, 0);
  for (int step = 0; step < TOTAL; ++step) {
    if (step) __syncthreads();
    {
      int m = tid >> 2, kq = (tid & 3) * 8;
      *(short8v*)&Ahs[m * LSTR + kq] = rAh;
      *(short8v*)&Als[m * LSTR + kq] = rAl;
    }
    if (MODE == 1) {
      int n = tid >> 2, kq2 = (tid & 3) * 8;
      float vals[8];
      if (STRIDED) {
        vals[0] = rBf[0].x; vals[1] = rBf[0].z; vals[2] = rBf[1].x; vals[3] = rBf[1].z;
        vals[4] = rBf[2].x; vals[5] = rBf[2].z; vals[6] = rBf[3].x; vals[7] = rBf[3].z;
      } else {
        vals[0] = rBf[0].x; vals[1] = rBf[0].y; vals[2] = rBf[0].z; vals[3] = rBf[0].w;
        vals[4] = rBf[1].x; vals[5] = rBf[1].y; vals[6] = rBf[1].z; vals[7] = rBf[1].w;
      }
      u16 hh[8], ll[8];
#pragma unroll
      for (int q = 0; q < 8; ++q) split2(vals[q], hh[q], ll[q]);
      *(short8v*)&Bhs[n * LSTR + kq2] = *(short8v*)hh;
      *(short8v*)&Bls[n * LSTR + kq2] = *(short8v*)ll;
    } else if (HALF) {
      int n = tid & 63, kq2 = (tid >> 6) * 8;
      *(short8v*)&Bhs[n * LSTR + kq2] = rBh0;
      *(short8v*)&Bls[n * LSTR + kq2] = rBl0;
    } else {
      int n = tid & 127, kq2 = (tid >> 7) * 16;
      *(short8v*)&Bhs[n * LSTR + kq2] = rBh0; *(short8v*)&Bhs[n * LSTR + kq2 + 8] = rBh1;
      *(short8v*)&Bls[n * LSTR + kq2] = rBl0; *(short8v*)&Bls[n * LSTR + kq2 + 8] = rBl1;
    }
    __syncthreads();
    int nxt = step + 1;
    if (nxt < TOTAL) {
      int tt = nxt >> 3, kk = (nxt & 7) * 32;
      LOAD_REGS(tt, kk);
    }
    short8v ah[2], al[2], bh[4], bl[4];
#pragma unroll
    for (int i = 0; i < 2; ++i) {
      int r = wr + i * 16 + lm;
      ah[i] = *(const short8v*)&Ahs[r * LSTR + lq * 8];
      al[i] = *(const short8v*)&Als[r * LSTR + lq * 8];
    }
#pragma unroll
    for (int j = 0; j < NJ; ++j) {
      int r = wc + j * 16 + lm;
      bh[j] = *(const short8v*)&Bhs[r * LSTR + lq * 8];
      bl[j] = *(const short8v*)&Bls[r * LSTR + lq * 8];
    }
#pragma unroll
    for (int i = 0; i < 2; ++i)
#pragma unroll
      for (int j = 0; j < NJ; ++j) {
        acc[i][j] = __builtin_amdgcn_mfma_f32_16x16x32_bf16(ah[i], bh[j], acc[i][j], 0, 0, 0);
        acc[i][j] = __builtin_amdgcn_mfma_f32_16x16x32_bf16(ah[i], bl[j], acc[i][j], 0, 0, 0);
        acc[i][j] = __builtin_amdgcn_mfma_f32_16x16x32_bf16(al[i], bh[j], acc[i][j], 0, 0, 0);
      }
  }

  // ---- epilogues (frag: col=lm, row=lq*4+r) ----
  if (MODE == 2 || MODE == 3) {
    float anewv[2][2][4];
#pragma unroll
    for (int i = 0; i < 2; ++i) {
#pragma unroll
      for (int r = 0; r < 4; ++r) {
        int grow = g * 256 + bym * 64 + wr + i * 16 + lq * 4 + r;
        float di = 0.f, ni = 0.f;
        if (MODE == 2) { di = dinv[grow]; ni = nrm[grow]; }
#pragma unroll
        for (int j = 0; j < NJ; ++j) {
          int gcol = col0 + wc + j * 16 + lm;
          size_t ci = (size_t)grow * 256 + gcol;
          float v = acc[i][j][r];
          if (MODE == 2) {
            int gj = g * 256 + gcol;
            Cf[ci] = v * di * dinv[gj] / (ni * nrm[gj] + ZEROF);
          } else {
            float nv = 0.5f * Cf[ci] + 0.5f * (1.f / (1.f + expf(-v)));
            Cf[ci] = nv;
            anewv[i][j][r] = nv;
          }
        }
      }
    }
    // ---- M1 build (layer-0 stageD only): M1[g,t][dst][src] = cnt * A_new[src][dst]
    if (MODE == 3 && Ch != nullptr) {
      const float* MCb = Bfp;            // interleaved (w, cnt) pairs
      float* M1 = (float*)Ch;
      float* Af = (float*)lds;           // [64][65] fp32 transpose tile
      __syncthreads();                   // all waves done with K-loop LDS reads
#pragma unroll
      for (int i = 0; i < 2; ++i)
#pragma unroll
        for (int j = 0; j < 2; ++j)
#pragma unroll
          for (int r = 0; r < 4; ++r)
            Af[(wc + j * 16 + lm) * 65 + (wr + i * 16 + lq * 4 + r)] = anewv[i][j][r];
      __syncthreads();
      int rr = tid >> 2;                 // tile-local dst (col of A)
      int q4 = (tid & 3) * 16;           // tile-local src start
#pragma unroll
      for (int t = 0; t < 3; ++t) {
        size_t cb = (((size_t)g * 3 + t) << 16) + (size_t)(col0 + rr) * 256 + bym * 64 + q4;
#pragma unroll
        for (int v = 0; v < 4; ++v) {
          const float4 p0 = *(const float4*)&MCb[(cb + v * 4) * 2];
          const float4 p1 = *(const float4*)&MCb[(cb + v * 4) * 2 + 4];
          float a0 = Af[rr * 65 + q4 + v * 4 + 0];
          float a1 = Af[rr * 65 + q4 + v * 4 + 1];
          float a2 = Af[rr * 65 + q4 + v * 4 + 2];
          float a3 = Af[rr * 65 + q4 + v * 4 + 3];
          *(float4*)&M1[cb + v * 4] = make_float4(p0.y * a0, p0.w * a1, p1.y * a2, p1.w * a3);
        }
      }
    }
  } else {
    float bsum[8];
    if (MODE == 1) {
#pragma unroll
      for (int i = 0; i < 2; ++i)
#pragma unroll
        for (int r = 0; r < 4; ++r) {
          int d = bym * 64 + wr + i * 16 + lq * 4 + r;
          bsum[i * 4 + r] = bias[d] + bias[256 + d] + bias[512 + d];
        }
    }
    u16 hv[32], lv[32];
#pragma unroll
    for (int i = 0; i < 2; ++i)
#pragma unroll
      for (int j = 0; j < NJ; ++j)
#pragma unroll
        for (int r = 0; r < 4; ++r) {
          float v = acc[i][j][r];
          if (MODE == 1) v = fmaxf(v + bsum[i * 4 + r], 0.f);
          split2(v, hv[(i * 4 + r) * NJ + j], lv[(i * 4 + r) * NJ + j]);
        }
    int ebase1 = (MODE == 1) ? (g * 256 + col0) : col0;
    int ebase2 = bym * 64;
    size_t estride = (MODE == 0) ? 8192 : 256;
#pragma unroll
    for (int ph = 0; ph < 2; ++ph) {
      __syncthreads();
      const u16* sv = ph ? lv : hv;
#pragma unroll
      for (int i = 0; i < 2; ++i)
#pragma unroll
        for (int j = 0; j < NJ; ++j)
#pragma unroll
          for (int r = 0; r < 4; ++r)
            Tt[(wc + j * 16 + lm) * TSTR + wr + i * 16 + lq * 4 + r] = sv[(i * 4 + r) * NJ + j];
      __syncthreads();
      u16* dst = ph ? Cl : Ch;
      int cc0 = tid >> 3, mm0 = (tid & 7) * 8;
#pragma unroll
      for (int it = 0; it < (HALF ? 2 : 4); ++it) {
        int cc = it * 32 + cc0;
        short8v v = *(const short8v*)&Tt[cc * TSTR + mm0];
        *(short8v*)&dst[(size_t)(ebase1 + cc) * estride + ebase2 + mm0] = v;
      }
    }
  }
}

// ===== prep: cvt(+flags) | transpose/split W | zero MC | norms+colsum+x-split =====
__global__ void k_prep(const int* __restrict__ e0, const int* __restrict__ e1,
                       const int* __restrict__ e2, const unsigned char* __restrict__ m0,
                       const unsigned char* __restrict__ m1,
                       const float* __restrict__ W, const float* __restrict__ T,
                       const float* __restrict__ x,
                       int* __restrict__ eo, float* __restrict__ emf, float* __restrict__ pmf,
                       u16* __restrict__ Wth, u16* __restrict__ Wtl,
                       float* __restrict__ MCzero,
                       float* __restrict__ nrm, float* __restrict__ Spart,
                       u16* __restrict__ Hh, u16* __restrict__ Hl,
                       int E2, int nCvt) {
  __shared__ float tile[32][33];
  __shared__ float inv[64];
  __shared__ int nz[2];
  const int b = blockIdx.x, tid = threadIdx.x;
  if (b < nCvt) {
    if (tid < 2) nz[tid] = 0;
    __syncthreads();
    if (e0[2 * tid + 1] != 0) atomicAdd(&nz[0], 1);
    int i4 = tid * 4;
    int c = (m0[i4 + 1] != 0) + (m0[i4 + 2] != 0) + (m0[i4 + 3] != 0);
    if (c) atomicAdd(&nz[1], c);
    __syncthreads();
    int fE = (nz[0] == 0), fM = (nz[1] == 0);
    int i = b * 256 + tid;
    if (i < E2) {
      eo[i] = fE ? e0[2 * i] : e0[i];
    } else if (i < 2 * E2) {
      int j = i - E2; eo[E2 + j] = fE ? e1[2 * j] : e1[j];
    } else if (i < 3 * E2) {
      int j = i - 2 * E2; eo[2 * E2 + j] = fE ? e2[2 * j] : e2[j];
    } else if (i < 3 * E2 + NND) {
      int j = i - 3 * E2; unsigned char v = fM ? m0[4 * j] : m0[j];
      emf[j] = 1.f - (float)(v != 0);
    } else if (i < 3 * E2 + 2 * NND) {
      int j = i - 3 * E2 - NND; unsigned char v = fM ? m1[4 * j] : m1[j];
      pmf[j] = 1.f - (float)(v != 0);
    }
  } else if (b < nCvt + 512) {
    int bb = b - nCvt;
    int mat = bb >> 6, rem = bb & 63;
    int k0 = (rem >> 3) * 32, n0 = (rem & 7) * 32;
    const float* src = (mat < 6) ? (W + (size_t)mat * 65536) : (T + (size_t)(mat - 6) * 65536);
    int r = tid >> 3, c4 = (tid & 7) * 4;
    const float4 v = *(const float4*)&src[(size_t)(k0 + r) * 256 + n0 + c4];
    tile[r][c4 + 0] = v.x; tile[r][c4 + 1] = v.y; tile[r][c4 + 2] = v.z; tile[r][c4 + 3] = v.w;
    __syncthreads();
    float o[4] = {tile[c4 + 0][r], tile[c4 + 1][r], tile[c4 + 2][r], tile[c4 + 3][r]};
    u16 hh[4], ll[4];
#pragma unroll
    for (int q = 0; q < 4; ++q) split2(o[q], hh[q], ll[q]);
    size_t off = (size_t)mat * 65536 + (size_t)(n0 + r) * 256 + k0 + c4;
    *(ushort4*)&Wth[off] = *(ushort4*)hh;
    *(ushort4*)&Wtl[off] = *(ushort4*)ll;
  } else if (b < nCvt + 512 + 3072) {
    int bb = b - nCvt - 512;           // zero 50 MB interleaved MC
    float4* p = (float4*)MCzero;
    size_t base = (size_t)bb * 1024 + tid;
    float4 z = make_float4(0.f, 0.f, 0.f, 0.f);
    p[base] = z; p[base + 256] = z; p[base + 512] = z; p[base + 768] = z;
  } else {
    int bn = b - nCvt - 512 - 3072;    // 0..127
    int n0 = bn * 64;
    int w = tid >> 6, lane = tid & 63;
    for (int it = 0; it < 16; ++it) {
      int nl = it * 4 + w;
      int node = n0 + nl;
      const float4 v = *(const float4*)&x[(size_t)node * 256 + lane * 4];
      u16 hh[4], ll[4];
      split2(v.x, hh[0], ll[0]); split2(v.y, hh[1], ll[1]);
      split2(v.z, hh[2], ll[2]); split2(v.w, hh[3], ll[3]);
      *(ushort4*)&Hh[(size_t)node * 256 + lane * 4] = *(ushort4*)hh;
      *(ushort4*)&Hl[(size_t)node * 256 + lane * 4] = *(ushort4*)ll;
      float s = wave_sum(v.x * v.x + v.y * v.y + v.z * v.z + v.w * v.w);
      if (lane == 0) { float nr = sqrtf(s); nrm[node] = nr; inv[nl] = 1.f / nr; }
    }
    __syncthreads();
    float s = 0.f;
    for (int i = 0; i < 64; ++i) s += x[(size_t)(n0 + i) * 256 + tid] * inv[i];
    Spart[bn * 256 + tid] = s;
  }
}

// ============ stage A (layer 0): mode0 GEMM | (w,cnt) edge scatter | dinv ============
__global__ __launch_bounds__(256, 2) void k_stageA(
    const u16* __restrict__ Hinh, const u16* __restrict__ Hinl,
    const u16* __restrict__ Wth, const u16* __restrict__ Wtl,
    u16* __restrict__ XWTh, u16* __restrict__ XWTl,
    const int* __restrict__ edges, const float* __restrict__ ew0,
    const float* __restrict__ ew1, const float* __restrict__ ew2,
    float* __restrict__ MC, int E_,
    const float* __restrict__ x, const float* __restrict__ Spart,
    const float* __restrict__ nrm, float* __restrict__ dinv) {
  __shared__ u16 lds[LDS_U16];
  const int b = blockIdx.x;
  if (b < 768) {
    mfma_body<0, false>(lds, Hinh, Hinl, Wth, Wtl, nullptr,
                        nullptr, XWTh, XWTl, nullptr, nullptr, nullptr,
                        b >> 7, b & 127, 0);
  } else if (b < 1024) {
    int bi = b - 768;
    for (int i = bi * 256 + threadIdx.x; i < 3 * E_; i += 65536) {
      int t = i / E_;
      int e = i - t * E_;
      const int* ei = edges + (size_t)t * 2 * E_;
      int src = ei[e], dst = ei[E_ + e];
      float wgt = (t == 0 ? ew0 : (t == 1 ? ew1 : ew2))[e];
      int gg = src >> 8;
      size_t idx = (((size_t)gg * 3 + t) << 16) + ((size_t)(dst & 255) << 8) + (src & 255);
      atomicAdd(&MC[idx * 2], wgt);       // value sum
      atomicAdd(&MC[idx * 2 + 1], 1.f);   // count (same cache line)
    }
  } else {
    float* Sl = (float*)lds;
    const int tid = threadIdx.x;
    float s = 0.f;
    for (int bb = 0; bb < 128; ++bb) s += Spart[bb * 256 + tid];
    Sl[tid] = s;
    __syncthreads();
    int base = (b - 1024) * 64;
    int w = tid >> 6, lane = tid & 63;
    const float4 sv = *(const float4*)&Sl[lane * 4];
    for (int it = 0; it < 16; ++it) {
      int node = base + it * 4 + w;
      const float4 v = *(const float4*)&x[(size_t)node * 256 + lane * 4];
      float s2 = wave_sum(v.x * sv.x + v.y * sv.y + v.z * sv.z + v.w * sv.w);
      if (lane == 0) {
        float rowsum = s2 / nrm[node];
        dinv[node] = rsqrtf(fabsf(rowsum) + ZEROF);
      }
    }
  }
}

// ============ stage B layer0: mode1 strided (512) | mode2 (512) ============
__global__ __launch_bounds__(256, 2) void k_stageB0(
    const u16* __restrict__ XWTh, const u16* __restrict__ XWTl,
    const float* __restrict__ MC,
    u16* __restrict__ Houth, u16* __restrict__ Houtl, const float* __restrict__ bias,
    const u16* __restrict__ xh, const u16* __restrict__ xl, float* __restrict__ Abuf,
    const float* __restrict__ nrm, const float* __restrict__ dinv) {
  __shared__ u16 lds[LDS_U16];
  const int b = blockIdx.x;
  if (b < 512) {
    int g = b & 31, r = b >> 5;
    mfma_body<1, true, true>(lds, XWTh, XWTl, nullptr, nullptr, MC,
                             nullptr, Houth, Houtl, nullptr, nullptr, bias,
                             r >> 2, r & 3, g);
  } else {
    int bb = b - 512;
    int g = bb & 31, r = bb >> 5;
    mfma_body<2, true>(lds, xh, xl, xh, xl, nullptr, Abuf, nullptr, nullptr,
                       nrm, dinv, nullptr, r >> 2, r & 3, g);
  }
}

// ============ stage B layer1: mode1 dense (512) ============
__global__ __launch_bounds__(256, 2) void k_stageB1(
    const u16* __restrict__ XWTh, const u16* __restrict__ XWTl,
    const float* __restrict__ Mb,
    u16* __restrict__ Houth, u16* __restrict__ Houtl, const float* __restrict__ bias) {
  __shared__ u16 lds[LDS_U16];
  const int b = blockIdx.x;
  int g = b & 31, r = b >> 5;
  mfma_body<1, true, false>(lds, XWTh, XWTl, nullptr, nullptr, Mb,
                            nullptr, Houth, Houtl, nullptr, nullptr, bias,
                            r >> 2, r & 3, g);
}

// ============ merged: mode4-l0 (512) + mode0-l1 (768) — both read H2 ============
__global__ __launch_bounds__(256, 2) void k_stageCA(
    const u16* __restrict__ Wth, const u16* __restrict__ Wtl,
    const u16* __restrict__ H2h, const u16* __restrict__ H2l,
    u16* __restrict__ tmph, u16* __restrict__ tmpl,
    u16* __restrict__ XWTh, u16* __restrict__ XWTl) {
  __shared__ u16 lds[LDS_U16];
  const int b = blockIdx.x;
  if (b < 512) {
    mfma_body<4, true>(lds, Wth + (size_t)6 * 65536, Wtl + (size_t)6 * 65536,
                       H2h, H2l, nullptr, nullptr, tmph, tmpl, nullptr, nullptr, nullptr,
                       b & 127, b >> 7, 0);
  } else {
    int bb = b - 512;
    mfma_body<0, false>(lds, H2h, H2l, Wth + (size_t)768 * 256, Wtl + (size_t)768 * 256,
                        nullptr, nullptr, XWTh, XWTl, nullptr, nullptr, nullptr,
                        bb >> 7, bb & 127, 0);
  }
}

// ============ stage C layer1: mode4 (512) ============
__global__ __launch_bounds__(256, 2) void k_stageC1(
    const u16* __restrict__ Wth, const u16* __restrict__ Wtl,
    const u16* __restrict__ Hh, const u16* __restrict__ Hl,
    u16* __restrict__ tmph, u16* __restrict__ tmpl) {
  __shared__ u16 lds[LDS_U16];
  const int b = blockIdx.x;
  mfma_body<4, true>(lds, Wth + (size_t)7 * 65536, Wtl + (size_t)7 * 65536,
                     Hh, Hl, nullptr, nullptr, tmph, tmpl, nullptr, nullptr, nullptr,
                     b & 127, b >> 7, 0);
}

// ============ stage D: mode3 A-update (+ M1 build when MC/M1 given) ============
__global__ __launch_bounds__(256, 2) void k_stageD(
    const u16* __restrict__ tmph, const u16* __restrict__ tmpl,
    const u16* __restrict__ Hh, const u16* __restrict__ Hl,
    float* __restrict__ Abuf, const float* __restrict__ MC, float* __restrict__ M1) {
  __shared__ u16 lds[LDS_U16];
  const int b = blockIdx.x;
  int g = b & 31, r = b >> 5;
  mfma_body<3, true>(lds, tmph, tmpl, Hh, Hl, MC, Abuf, (u16*)M1, nullptr,
                     nullptr, nullptr, nullptr, r >> 2, r & 3, g);
}

// ============ fused maps ============
__global__ void k_maps(const float* __restrict__ Abuf, const float* __restrict__ emf,
                       const float* __restrict__ pmf, float* __restrict__ out) {
  __shared__ float sme[256], smp[256], red[256];
  const int g = blockIdx.x, tid = threadIdx.x, w = tid >> 6, lane = tid & 63;
  const int j0 = g * 256 + lane * 4;
  const float4 pmv = *(const float4*)&pmf[j0];
  const float4 emv = *(const float4*)&emf[j0];
  for (int it = 0; it < 64; ++it) {
    int nl = it * 4 + w;
    const float4 a = *(const float4*)&Abuf[((size_t)g * 256 + nl) * 256 + lane * 4];
    float me = a.x * pmv.x + a.y * pmv.y + a.z * pmv.z + a.w * pmv.w;
    float mp = a.x * emv.x + a.y * emv.y + a.z * emv.z + a.w * emv.w;
#pragma unroll
    for (int off = 32; off > 0; off >>= 1) {
      me += __shfl_down(me, off, 64);
      mp += __shfl_down(mp, off, 64);
    }
    if (lane == 0) { sme[nl] = me; smp[nl] = mp; }
  }
  __syncthreads();
  for (int which = 0; which < 2; ++which) {
    float v = which ? smp[tid] : sme[tid];
    red[tid] = v; __syncthreads();
    for (int s = 128; s > 0; s >>= 1) { if (tid < s) red[tid] = fminf(red[tid], red[tid + s]); __syncthreads(); }
    float mn = red[0]; __syncthreads();
    red[tid] = v; __syncthreads();
    for (int s = 128; s > 0; s >>= 1) { if (tid < s) red[tid] = fmaxf(red[tid], red[tid + s]); __syncthreads(); }
    float mx = red[0]; __syncthreads();
    float m = (v - mn) / (mx - mn + ZEROF);
    red[tid] = m; __syncthreads();
    for (int s = 128; s > 0; s >>= 1) { if (tid < s) red[tid] += red[tid + s]; __syncthreads(); }
    float sum = red[0]; __syncthreads();
    out[which * NND + g * 256 + tid] = m / (sum + ZEROF);
  }
}

// ================= launch =================
extern "C" void kernel_launch(void* const* d_in, const int* in_sizes, int n_in,
                              void* d_out, int out_size, void* d_ws, size_t ws_size,
                              hipStream_t stream) {
  const float* x = (const float*)d_in[0];
  const unsigned char* em_raw = (const unsigned char*)d_in[7];
  const unsigned char* pm_raw = (const unsigned char*)d_in[8];
  const float* W  = (const float*)d_in[9];
  const float* bg = (const float*)d_in[10];
  const float* T  = (const float*)d_in[11];
  float* out = (float*)d_out;
  const int E_ = in_sizes[2];
  const int E2 = 2 * E_;

  float* ws = (float*)d_ws;
  size_t o = 0;
  float* Abuf = ws + o; o += (size_t)NND * 256;
  float* MC   = ws + o; o += (size_t)2 * NGRP * 3 * 65536;   // interleaved (w,cnt), 50 MB
  float* Mb1  = ws + o; o += (size_t)NGRP * 3 * 65536;       // layer-1 M (dense, no zeroing)
  u16* Hh   = (u16*)(ws + o); o += (size_t)NND * 256 / 2;
  u16* Hl   = (u16*)(ws + o); o += (size_t)NND * 256 / 2;
  u16* H2h  = (u16*)(ws + o); o += (size_t)NND * 256 / 2;
  u16* H2l  = (u16*)(ws + o); o += (size_t)NND * 256 / 2;
  u16* tmph = (u16*)(ws + o); o += (size_t)NND * 256 / 2;
  u16* tmpl = (u16*)(ws + o); o += (size_t)NND * 256 / 2;
  u16* XWTh = (u16*)(ws + o); o += (size_t)768 * NND / 2;
  u16* XWTl = (u16*)(ws + o); o += (size_t)768 * NND / 2;
  u16* Wth  = (u16*)(ws + o); o += (size_t)8 * 65536 / 2;
  u16* Wtl  = (u16*)(ws + o); o += (size_t)8 * 65536 / 2;
  float* nrm   = ws + o; o += NND;
  float* dinv  = ws + o; o += NND;
  float* Spart = ws + o; o += 128 * 256;
  float* emf   = ws + o; o += NND;
  float* pmf   = ws + o; o += NND;
  int* edges   = (int*)(ws + o); o += (size_t)3 * E2;

  const float* ew0 = (const float*)d_in[2];
  const float* ew1 = (const float*)d_in[4];
  const float* ew2 = (const float*)d_in[6];

  const int nCvt = (3 * E2 + 2 * NND + 255) / 256;

  k_prep<<<nCvt + 512 + 3072 + 128, 256, 0, stream>>>(
      (const int*)d_in[1], (const int*)d_in[3], (const int*)d_in[5], em_raw, pm_raw,
      W, T, x, edges, emf, pmf, Wth, Wtl, MC, nrm, Spart, Hh, Hl, E2, nCvt);

  // ---- layer 0 ----
  k_stageA<<<1152, 256, 0, stream>>>(Hh, Hl, Wth, Wtl, XWTh, XWTl,
                                     edges, ew0, ew1, ew2, MC, E_,
                                     x, Spart, nrm, dinv);
  k_stageB0<<<1024, 256, 0, stream>>>(XWTh, XWTl, MC, H2h, H2l, bg,
                                      Hh, Hl, Abuf, nrm, dinv);
  // mode4-l0 (tmp = H2@T0) + mode0-l1 (XWT = (H2@Wcat1)^T), both depend only on H2
  k_stageCA<<<1280, 256, 0, stream>>>(Wth, Wtl, H2h, H2l, tmph, tmpl, XWTh, XWTl);
  // A-update l0 + M1 = cnt * A_new^T (replaces the layer-1 scatter+gather)
  k_stageD<<<512, 256, 0, stream>>>(tmph, tmpl, H2h, H2l, Abuf, MC, Mb1);

  // ---- layer 1 ----
  k_stageB1<<<512, 256, 0, stream>>>(XWTh, XWTl, Mb1, Hh, Hl, bg + 768);
  k_stageC1<<<512, 256, 0, stream>>>(Wth, Wtl, Hh, Hl, tmph, tmpl);
  k_stageD<<<512, 256, 0, stream>>>(tmph, tmpl, Hh, Hl, Abuf, nullptr, nullptr);

  k_maps<<<NGRP, 256, 0, stream>>>(Abuf, emf, pmf, out);
}

// Round 14
// 283.832 us; speedup vs baseline: 1.2071x; 1.2071x over previous
//
#include <hip/hip_runtime.h>

#define NND   8192
#define DDIM  256
#define NGRP  32
#define ZEROF 1e-8f
#define LSTR  40   // K-loop LDS row stride in u16 (80 B: 16B-aligned, 2-way banks free)
#define TSTR  72   // epilogue transpose tile stride in u16 (144 B)
// flat LDS layout (u16 units). TT aliases the B-staging buffers (dead after the
// K-loop, separated by __syncthreads) -> 30 KB/block -> 5 blocks/CU.
#define OFF_AH 0
#define OFF_AL 2560
#define OFF_BH 5120
#define OFF_BL 10240
#define OFF_TT 5120          // aliases BH/BL region: 128*72=9216 u16 <= 10240
#define LDS_U16 15360

typedef unsigned short u16;
typedef __attribute__((ext_vector_type(8))) short short8v;
typedef __attribute__((ext_vector_type(4))) float float4v;

__device__ inline u16 f2bf(float x) {
  unsigned u = __float_as_uint(x);
  u += 0x7fffu + ((u >> 16) & 1u);
  return (u16)(u >> 16);
}
__device__ inline float bf2f(u16 h) { return __uint_as_float((unsigned)h << 16); }
__device__ inline void split2(float x, u16& h, u16& l) {
  h = f2bf(x);
  l = f2bf(x - bf2f(h));
}

__device__ inline float wave_sum(float v) {
#pragma unroll
  for (int off = 32; off > 0; off >>= 1) v += __shfl_down(v, off, 64);
  return v;
}

// ================= unified split-bf16 MFMA GEMM body =================
// C-tile 64 x (HALF?64:128), 4 waves, 16x16x32 bf16 MFMA, split-bf16x3.
// MODE 0: XWT[c][node] = (H @ Wcat)^T      a=H(node), b=Wt(c)       [full]
// MODE 1: Hout = relu(b3 + M @ XWcat)      a=XWT(d), b=M fp32, K=768 [half]
// MODE 2: A = (x.xT)*di*dj/(ni*nj+eps)     a=b=x                    [half]
// MODE 3: A = 0.5A + 0.5 sigmoid(t.HT)     a=tmp, b=H               [half]
// MODE 4: tmp[node][d] = H @ T             a=Tt(d), b=H(node)       [half]
#define LOAD_REGS(tt, kk)                                                                   \
  {                                                                                         \
    int m_ = tid >> 2, kq_ = (tid & 3) * 8;                                                 \
    size_t aoff_;                                                                           \
    if (MODE == 1)                                                                          \
      aoff_ = (size_t)((tt) * 256 + bym * 64 + m_) * 8192 + (size_t)(g * 256 + (kk) + kq_); \
    else if (MODE == 2 || MODE == 3)                                                        \
      aoff_ = (size_t)(g * 256 + bym * 64 + m_) * 256 + (kk) + kq_;                         \
    else                                                                                    \
      aoff_ = (size_t)(bym * 64 + m_) * 256 + (kk) + kq_;                                   \
    rAh = *(const short8v*)&Ah_g[aoff_];                                                    \
    rAl = *(const short8v*)&Al_g[aoff_];                                                    \
    if (MODE == 1) {                                                                        \
      int n_ = tid >> 2, kq2_ = (tid & 3) * 8;                                              \
      const float* pb_ = Bfp + (((size_t)g * 3 + (tt)) << 16) +                             \
                         (size_t)(col0 + n_) * 256 + (kk) + kq2_;                           \
      rBf[0] = *(const float4*)pb_;                                                         \
      rBf[1] = *(const float4*)(pb_ + 4);                                                   \
    } else if (HALF) {                                                                      \
      int n_ = tid & 63, kq2_ = (tid >> 6) * 8;                                             \
      size_t boff_ = (size_t)(((MODE == 2 || MODE == 3) ? g * 256 : 0) + col0 + n_) * 256   \
                     + (kk) + kq2_;                                                         \
      rBh0 = *(const short8v*)&Bh_g[boff_];                                                 \
      rBl0 = *(const short8v*)&Bl_g[boff_];                                                 \
    } else {                                                                                \
      int n_ = tid & 127, kq2_ = (tid >> 7) * 16;                                           \
      size_t boff_ = (size_t)(col0 + n_) * 256 + (kk) + kq2_;                               \
      rBh0 = *(const short8v*)&Bh_g[boff_]; rBh1 = *(const short8v*)&Bh_g[boff_ + 8];       \
      rBl0 = *(const short8v*)&Bl_g[boff_]; rBl1 = *(const short8v*)&Bl_g[boff_ + 8];       \
    }                                                                                       \
  }

template<int MODE, bool HALF>
__device__ __forceinline__ void mfma_body(
    u16* lds,
    const u16* __restrict__ Ah_g, const u16* __restrict__ Al_g,
    const u16* __restrict__ Bh_g, const u16* __restrict__ Bl_g,
    const float* __restrict__ Bfp,
    float* __restrict__ Cf, u16* __restrict__ Ch, u16* __restrict__ Cl,
    const float* __restrict__ nrm, const float* __restrict__ dinv,
    const float* __restrict__ bias,
    int bxm, int bym, int g) {
  u16* Ahs = lds + OFF_AH;
  u16* Als = lds + OFF_AL;
  u16* Bhs = lds + OFF_BH;
  u16* Bls = lds + OFF_BL;
  u16* Tt  = lds + OFF_TT;    // aliases Bhs/Bls — only used after K-loop + sync
  const int NJ = HALF ? 2 : 4;
  const int tid = threadIdx.x;
  const int col0 = bxm * (HALF ? 64 : 128);
  const int w = tid >> 6, lane = tid & 63;
  const int lm = lane & 15, lq = lane >> 4;
  const int wr = (w >> 1) * 32, wc = (w & 1) * (HALF ? 32 : 64);

  float4v acc[2][4];
#pragma unroll
  for (int i = 0; i < 2; ++i)
#pragma unroll
    for (int j = 0; j < NJ; ++j) acc[i][j] = (float4v)0.f;

  short8v rAh, rAl, rBh0, rBh1, rBl0, rBl1;
  float4 rBf[2];
  const int TOTAL = (MODE == 1) ? 24 : 8;

  LOAD_REGS(0, 0);
  for (int step = 0; step < TOTAL; ++step) {
    if (step) __syncthreads();
    {
      int m = tid >> 2, kq = (tid & 3) * 8;
      *(short8v*)&Ahs[m * LSTR + kq] = rAh;
      *(short8v*)&Als[m * LSTR + kq] = rAl;
    }
    if (MODE == 1) {
      int n = tid >> 2, kq2 = (tid & 3) * 8;
      u16 hh[8], ll[8];
      split2(rBf[0].x, hh[0], ll[0]); split2(rBf[0].y, hh[1], ll[1]);
      split2(rBf[0].z, hh[2], ll[2]); split2(rBf[0].w, hh[3], ll[3]);
      split2(rBf[1].x, hh[4], ll[4]); split2(rBf[1].y, hh[5], ll[5]);
      split2(rBf[1].z, hh[6], ll[6]); split2(rBf[1].w, hh[7], ll[7]);
      *(short8v*)&Bhs[n * LSTR + kq2] = *(short8v*)hh;
      *(short8v*)&Bls[n * LSTR + kq2] = *(short8v*)ll;
    } else if (HALF) {
      int n = tid & 63, kq2 = (tid >> 6) * 8;
      *(short8v*)&Bhs[n * LSTR + kq2] = rBh0;
      *(short8v*)&Bls[n * LSTR + kq2] = rBl0;
    } else {
      int n = tid & 127, kq2 = (tid >> 7) * 16;
      *(short8v*)&Bhs[n * LSTR + kq2] = rBh0; *(short8v*)&Bhs[n * LSTR + kq2 + 8] = rBh1;
      *(short8v*)&Bls[n * LSTR + kq2] = rBl0; *(short8v*)&Bls[n * LSTR + kq2 + 8] = rBl1;
    }
    __syncthreads();
    int nxt = step + 1;
    if (nxt < TOTAL) {
      int tt = nxt >> 3, kk = (nxt & 7) * 32;
      LOAD_REGS(tt, kk);
    }
    short8v ah[2], al[2], bh[4], bl[4];
#pragma unroll
    for (int i = 0; i < 2; ++i) {
      int r = wr + i * 16 + lm;
      ah[i] = *(const short8v*)&Ahs[r * LSTR + lq * 8];
      al[i] = *(const short8v*)&Als[r * LSTR + lq * 8];
    }
#pragma unroll
    for (int j = 0; j < NJ; ++j) {
      int r = wc + j * 16 + lm;
      bh[j] = *(const short8v*)&Bhs[r * LSTR + lq * 8];
      bl[j] = *(const short8v*)&Bls[r * LSTR + lq * 8];
    }
#pragma unroll
    for (int i = 0; i < 2; ++i)
#pragma unroll
      for (int j = 0; j < NJ; ++j) {
        acc[i][j] = __builtin_amdgcn_mfma_f32_16x16x32_bf16(ah[i], bh[j], acc[i][j], 0, 0, 0);
        acc[i][j] = __builtin_amdgcn_mfma_f32_16x16x32_bf16(ah[i], bl[j], acc[i][j], 0, 0, 0);
        acc[i][j] = __builtin_amdgcn_mfma_f32_16x16x32_bf16(al[i], bh[j], acc[i][j], 0, 0, 0);
      }
  }

  // ---- epilogues (frag: col=lm, row=lq*4+r) ----
  if (MODE == 2 || MODE == 3) {
#pragma unroll
    for (int i = 0; i < 2; ++i) {
#pragma unroll
      for (int r = 0; r < 4; ++r) {
        int grow = g * 256 + bym * 64 + wr + i * 16 + lq * 4 + r;
        float di = 0.f, ni = 0.f;
        if (MODE == 2) { di = dinv[grow]; ni = nrm[grow]; }
#pragma unroll
        for (int j = 0; j < NJ; ++j) {
          int gcol = col0 + wc + j * 16 + lm;
          size_t ci = (size_t)grow * 256 + gcol;
          float v = acc[i][j][r];
          if (MODE == 2) {
            int gj = g * 256 + gcol;
            Cf[ci] = v * di * dinv[gj] / (ni * nrm[gj] + ZEROF);
          } else {
            Cf[ci] = 0.5f * Cf[ci] + 0.5f * (1.f / (1.f + expf(-v)));
          }
        }
      }
    }
  } else {
    float bsum[8];
    if (MODE == 1) {
#pragma unroll
      for (int i = 0; i < 2; ++i)
#pragma unroll
        for (int r = 0; r < 4; ++r) {
          int d = bym * 64 + wr + i * 16 + lq * 4 + r;
          bsum[i * 4 + r] = bias[d] + bias[256 + d] + bias[512 + d];
        }
    }
    u16 hv[32], lv[32];
#pragma unroll
    for (int i = 0; i < 2; ++i)
#pragma unroll
      for (int j = 0; j < NJ; ++j)
#pragma unroll
        for (int r = 0; r < 4; ++r) {
          float v = acc[i][j][r];
          if (MODE == 1) v = fmaxf(v + bsum[i * 4 + r], 0.f);
          split2(v, hv[(i * 4 + r) * NJ + j], lv[(i * 4 + r) * NJ + j]);
        }
    int ebase1 = (MODE == 1) ? (g * 256 + col0) : col0;
    int ebase2 = bym * 64;
    size_t estride = (MODE == 0) ? 8192 : 256;
#pragma unroll
    for (int ph = 0; ph < 2; ++ph) {
      __syncthreads();
      const u16* sv = ph ? lv : hv;
#pragma unroll
      for (int i = 0; i < 2; ++i)
#pragma unroll
        for (int j = 0; j < NJ; ++j)
#pragma unroll
          for (int r = 0; r < 4; ++r)
            Tt[(wc + j * 16 + lm) * TSTR + wr + i * 16 + lq * 4 + r] = sv[(i * 4 + r) * NJ + j];
      __syncthreads();
      u16* dst = ph ? Cl : Ch;
      int cc0 = tid >> 3, mm0 = (tid & 7) * 8;
#pragma unroll
      for (int it = 0; it < (HALF ? 2 : 4); ++it) {
        int cc = it * 32 + cc0;
        short8v v = *(const short8v*)&Tt[cc * TSTR + mm0];
        *(short8v*)&dst[(size_t)(ebase1 + cc) * estride + ebase2 + mm0] = v;
      }
    }
  }
}

// ===== prep: cvt(+flags) | transpose/split W | zero M | norms+colsum-partials+x-split =====
__global__ void k_prep(const int* __restrict__ e0, const int* __restrict__ e1,
                       const int* __restrict__ e2, const unsigned char* __restrict__ m0,
                       const unsigned char* __restrict__ m1,
                       const float* __restrict__ W, const float* __restrict__ T,
                       const float* __restrict__ x,
                       int* __restrict__ eo, float* __restrict__ emf, float* __restrict__ pmf,
                       u16* __restrict__ Wth, u16* __restrict__ Wtl,
                       float* __restrict__ Mzero,
                       float* __restrict__ nrm, float* __restrict__ Spart,
                       u16* __restrict__ Hh, u16* __restrict__ Hl,
                       int E2, int nCvt) {
  __shared__ float tile[32][33];
  __shared__ float inv[64];
  __shared__ int nz[2];
  const int b = blockIdx.x, tid = threadIdx.x;
  if (b < nCvt) {
    if (tid < 2) nz[tid] = 0;
    __syncthreads();
    if (e0[2 * tid + 1] != 0) atomicAdd(&nz[0], 1);
    int i4 = tid * 4;
    int c = (m0[i4 + 1] != 0) + (m0[i4 + 2] != 0) + (m0[i4 + 3] != 0);
    if (c) atomicAdd(&nz[1], c);
    __syncthreads();
    int fE = (nz[0] == 0), fM = (nz[1] == 0);
    int i = b * 256 + tid;
    if (i < E2) {
      eo[i] = fE ? e0[2 * i] : e0[i];
    } else if (i < 2 * E2) {
      int j = i - E2; eo[E2 + j] = fE ? e1[2 * j] : e1[j];
    } else if (i < 3 * E2) {
      int j = i - 2 * E2; eo[2 * E2 + j] = fE ? e2[2 * j] : e2[j];
    } else if (i < 3 * E2 + NND) {
      int j = i - 3 * E2; unsigned char v = fM ? m0[4 * j] : m0[j];
      emf[j] = 1.f - (float)(v != 0);
    } else if (i < 3 * E2 + 2 * NND) {
      int j = i - 3 * E2 - NND; unsigned char v = fM ? m1[4 * j] : m1[j];
      pmf[j] = 1.f - (float)(v != 0);
    }
  } else if (b < nCvt + 512) {
    int bb = b - nCvt;
    int mat = bb >> 6, rem = bb & 63;
    int k0 = (rem >> 3) * 32, n0 = (rem & 7) * 32;
    const float* src = (mat < 6) ? (W + (size_t)mat * 65536) : (T + (size_t)(mat - 6) * 65536);
    int r = tid >> 3, c4 = (tid & 7) * 4;
    const float4 v = *(const float4*)&src[(size_t)(k0 + r) * 256 + n0 + c4];
    tile[r][c4 + 0] = v.x; tile[r][c4 + 1] = v.y; tile[r][c4 + 2] = v.z; tile[r][c4 + 3] = v.w;
    __syncthreads();
    float o[4] = {tile[c4 + 0][r], tile[c4 + 1][r], tile[c4 + 2][r], tile[c4 + 3][r]};
    u16 hh[4], ll[4];
#pragma unroll
    for (int q = 0; q < 4; ++q) split2(o[q], hh[q], ll[q]);
    size_t off = (size_t)mat * 65536 + (size_t)(n0 + r) * 256 + k0 + c4;
    *(ushort4*)&Wth[off] = *(ushort4*)hh;
    *(ushort4*)&Wtl[off] = *(ushort4*)ll;
  } else if (b < nCvt + 512 + 3072) {
    int bb = b - nCvt - 512;           // zero 2x25MB of M
    float4* p = (float4*)Mzero;
    size_t base = (size_t)bb * 1024 + tid;
    float4 z = make_float4(0.f, 0.f, 0.f, 0.f);
    p[base] = z; p[base + 256] = z; p[base + 512] = z; p[base + 768] = z;
  } else {
    int bn = b - nCvt - 512 - 3072;    // 0..127
    int n0 = bn * 64;
    int w = tid >> 6, lane = tid & 63;
    for (int it = 0; it < 16; ++it) {
      int nl = it * 4 + w;
      int node = n0 + nl;
      const float4 v = *(const float4*)&x[(size_t)node * 256 + lane * 4];
      u16 hh[4], ll[4];
      split2(v.x, hh[0], ll[0]); split2(v.y, hh[1], ll[1]);
      split2(v.z, hh[2], ll[2]); split2(v.w, hh[3], ll[3]);
      *(ushort4*)&Hh[(size_t)node * 256 + lane * 4] = *(ushort4*)hh;
      *(ushort4*)&Hl[(size_t)node * 256 + lane * 4] = *(ushort4*)ll;
      float s = wave_sum(v.x * v.x + v.y * v.y + v.z * v.z + v.w * v.w);
      if (lane == 0) { float nr = sqrtf(s); nrm[node] = nr; inv[nl] = 1.f / nr; }
    }
    __syncthreads();
    float s = 0.f;
    for (int i = 0; i < 64; ++i) s += x[(size_t)(n0 + i) * 256 + tid] * inv[i];
    Spart[bn * 256 + tid] = s;
  }
}

// ============ stage A: mode0 GEMM (768) | edge scatter (512) | (l0) dinv (128) ============
__global__ __launch_bounds__(256, 2) void k_stageA(
    const u16* __restrict__ Hinh, const u16* __restrict__ Hinl,
    const u16* __restrict__ Wth, const u16* __restrict__ Wtl, int l,
    u16* __restrict__ XWTh, u16* __restrict__ XWTl,
    const int* __restrict__ edges, const float* __restrict__ ew0,
    const float* __restrict__ ew1, const float* __restrict__ ew2,
    const float* __restrict__ Abuf, float* __restrict__ Mb, int E_,
    const float* __restrict__ x, const float* __restrict__ Spart,
    const float* __restrict__ nrm, float* __restrict__ dinv) {
  __shared__ u16 lds[LDS_U16];
  const int b = blockIdx.x;
  if (b < 768) {
    // XCD-aware: same H row-block -> same b mod 8 -> same XCD L2
    mfma_body<0, false>(lds, Hinh, Hinl, Wth + (size_t)l * 768 * 256,
                        Wtl + (size_t)l * 768 * 256, nullptr,
                        nullptr, XWTh, XWTl, nullptr, nullptr, nullptr,
                        b >> 7, b & 127, 0);
  } else if (b < 1280) {
    // 512 scatter blocks (2x round-12 width): more resident waves -> more
    // outstanding atomics -> shorter latency-bound critical path
    int bi = b - 768;
    for (int i = bi * 256 + threadIdx.x; i < 3 * E_; i += 131072) {
      int t = i / E_;
      int e = i - t * E_;
      const int* ei = edges + (size_t)t * 2 * E_;
      int src = ei[e], dst = ei[E_ + e];
      float wgt = l ? Abuf[(size_t)src * 256 + (dst & 255)]
                    : (t == 0 ? ew0 : (t == 1 ? ew1 : ew2))[e];
      int gg = src >> 8;
      atomicAdd(&Mb[(((size_t)gg * 3 + t) << 16) + ((size_t)(dst & 255) << 8) + (src & 255)],
                wgt);
    }
  } else {
    float* Sl = (float*)lds;
    const int tid = threadIdx.x;
    float s = 0.f;
    for (int bb = 0; bb < 128; ++bb) s += Spart[bb * 256 + tid];
    Sl[tid] = s;
    __syncthreads();
    int base = (b - 1280) * 64;
    int w = tid >> 6, lane = tid & 63;
    const float4 sv = *(const float4*)&Sl[lane * 4];
    for (int it = 0; it < 16; ++it) {
      int node = base + it * 4 + w;
      const float4 v = *(const float4*)&x[(size_t)node * 256 + lane * 4];
      float s2 = wave_sum(v.x * sv.x + v.y * sv.y + v.z * sv.z + v.w * sv.w);
      if (lane == 0) {
        float rowsum = s2 / nrm[node];
        dinv[node] = rsqrtf(fabsf(rowsum) + ZEROF);
      }
    }
  }
}

// ============ stage B: mode1 (half, 512) | (l0 only) mode2 (half, 512) ============
__global__ __launch_bounds__(256, 2) void k_stageB(
    const u16* __restrict__ XWTh, const u16* __restrict__ XWTl,
    const float* __restrict__ Mb,
    u16* __restrict__ Houth, u16* __restrict__ Houtl, const float* __restrict__ bias,
    const u16* __restrict__ xh, const u16* __restrict__ xl, float* __restrict__ Abuf,
    const float* __restrict__ nrm, const float* __restrict__ dinv) {
  __shared__ u16 lds[LDS_U16];
  const int b = blockIdx.x;
  if (b < 512) {
    int g = b & 31, r = b >> 5;        // r: 0..15 -> bym 0..3, bxm 0..3
    mfma_body<1, true>(lds, XWTh, XWTl, nullptr, nullptr, Mb,
                       nullptr, Houth, Houtl, nullptr, nullptr, bias,
                       r >> 2, r & 3, g);
  } else {
    int bb = b - 512;
    int g = bb & 31, r = bb >> 5;
    mfma_body<2, true>(lds, xh, xl, xh, xl, nullptr, Abuf, nullptr, nullptr,
                       nrm, dinv, nullptr, r >> 2, r & 3, g);
  }
}

// ============ stage C: mode4 (half, 512): tmp = H @ T ============
__global__ __launch_bounds__(256, 2) void k_stageC(
    const u16* __restrict__ Wth, const u16* __restrict__ Wtl, int l,
    const u16* __restrict__ Hh, const u16* __restrict__ Hl,
    u16* __restrict__ tmph, u16* __restrict__ tmpl) {
  __shared__ u16 lds[LDS_U16];
  const int b = blockIdx.x;
  mfma_body<4, true>(lds, Wth + (size_t)(6 + l) * 65536, Wtl + (size_t)(6 + l) * 65536,
                     Hh, Hl, nullptr, nullptr, tmph, tmpl, nullptr, nullptr, nullptr,
                     b & 127, b >> 7, 0);
}

// ============ stage D: mode3 (half, 512): A update ============
__global__ __launch_bounds__(256, 2) void k_stageD(
    const u16* __restrict__ tmph, const u16* __restrict__ tmpl,
    const u16* __restrict__ Hh, const u16* __restrict__ Hl,
    float* __restrict__ Abuf) {
  __shared__ u16 lds[LDS_U16];
  const int b = blockIdx.x;
  int g = b & 31, r = b >> 5;
  mfma_body<3, true>(lds, tmph, tmpl, Hh, Hl, nullptr, Abuf, nullptr, nullptr,
                     nullptr, nullptr, nullptr, r >> 2, r & 3, g);
}

// ============ fused maps ============
__global__ void k_maps(const float* __restrict__ Abuf, const float* __restrict__ emf,
                       const float* __restrict__ pmf, float* __restrict__ out) {
  __shared__ float sme[256], smp[256], red[256];
  const int g = blockIdx.x, tid = threadIdx.x, w = tid >> 6, lane = tid & 63;
  const int j0 = g * 256 + lane * 4;
  const float4 pmv = *(const float4*)&pmf[j0];
  const float4 emv = *(const float4*)&emf[j0];
  for (int it = 0; it < 64; ++it) {
    int nl = it * 4 + w;
    const float4 a = *(const float4*)&Abuf[((size_t)g * 256 + nl) * 256 + lane * 4];
    float me = a.x * pmv.x + a.y * pmv.y + a.z * pmv.z + a.w * pmv.w;
    float mp = a.x * emv.x + a.y * emv.y + a.z * emv.z + a.w * emv.w;
#pragma unroll
    for (int off = 32; off > 0; off >>= 1) {
      me += __shfl_down(me, off, 64);
      mp += __shfl_down(mp, off, 64);
    }
    if (lane == 0) { sme[nl] = me; smp[nl] = mp; }
  }
  __syncthreads();
  for (int which = 0; which < 2; ++which) {
    float v = which ? smp[tid] : sme[tid];
    red[tid] = v; __syncthreads();
    for (int s = 128; s > 0; s >>= 1) { if (tid < s) red[tid] = fminf(red[tid], red[tid + s]); __syncthreads(); }
    float mn = red[0]; __syncthreads();
    red[tid] = v; __syncthreads();
    for (int s = 128; s > 0; s >>= 1) { if (tid < s) red[tid] = fmaxf(red[tid], red[tid + s]); __syncthreads(); }
    float mx = red[0]; __syncthreads();
    float m = (v - mn) / (mx - mn + ZEROF);
    red[tid] = m; __syncthreads();
    for (int s = 128; s > 0; s >>= 1) { if (tid < s) red[tid] += red[tid + s]; __syncthreads(); }
    float sum = red[0]; __syncthreads();
    out[which * NND + g * 256 + tid] = m / (sum + ZEROF);
  }
}

// ================= launch =================
extern "C" void kernel_launch(void* const* d_in, const int* in_sizes, int n_in,
                              void* d_out, int out_size, void* d_ws, size_t ws_size,
                              hipStream_t stream) {
  const float* x = (const float*)d_in[0];
  const unsigned char* em_raw = (const unsigned char*)d_in[7];
  const unsigned char* pm_raw = (const unsigned char*)d_in[8];
  const float* W  = (const float*)d_in[9];
  const float* bg = (const float*)d_in[10];
  const float* T  = (const float*)d_in[11];
  float* out = (float*)d_out;
  const int E_ = in_sizes[2];
  const int E2 = 2 * E_;

  float* ws = (float*)d_ws;
  size_t o = 0;
  float* Abuf = ws + o; o += (size_t)NND * 256;
  float* Mb3  = ws + o; o += (size_t)2 * NGRP * 3 * 65536;
  u16* Hh   = (u16*)(ws + o); o += (size_t)NND * 256 / 2;
  u16* Hl   = (u16*)(ws + o); o += (size_t)NND * 256 / 2;
  u16* H2h  = (u16*)(ws + o); o += (size_t)NND * 256 / 2;
  u16* H2l  = (u16*)(ws + o); o += (size_t)NND * 256 / 2;
  u16* tmph = (u16*)(ws + o); o += (size_t)NND * 256 / 2;
  u16* tmpl = (u16*)(ws + o); o += (size_t)NND * 256 / 2;
  u16* XWTh = (u16*)(ws + o); o += (size_t)768 * NND / 2;
  u16* XWTl = (u16*)(ws + o); o += (size_t)768 * NND / 2;
  u16* Wth  = (u16*)(ws + o); o += (size_t)8 * 65536 / 2;
  u16* Wtl  = (u16*)(ws + o); o += (size_t)8 * 65536 / 2;
  float* nrm   = ws + o; o += NND;
  float* dinv  = ws + o; o += NND;
  float* Spart = ws + o; o += 128 * 256;
  float* emf   = ws + o; o += NND;
  float* pmf   = ws + o; o += NND;
  int* edges   = (int*)(ws + o); o += (size_t)3 * E2;

  const float* ew0 = (const float*)d_in[2];
  const float* ew1 = (const float*)d_in[4];
  const float* ew2 = (const float*)d_in[6];
  float* Mb_l0 = Mb3;
  float* Mb_l1 = Mb3 + (size_t)NGRP * 3 * 65536;

  const int nCvt = (3 * E2 + 2 * NND + 255) / 256;

  k_prep<<<nCvt + 512 + 3072 + 128, 256, 0, stream>>>(
      (const int*)d_in[1], (const int*)d_in[3], (const int*)d_in[5], em_raw, pm_raw,
      W, T, x, edges, emf, pmf, Wth, Wtl, Mb3, nrm, Spart, Hh, Hl, E2, nCvt);

  // ---- layer 0 ----
  k_stageA<<<1408, 256, 0, stream>>>(Hh, Hl, Wth, Wtl, 0, XWTh, XWTl,
                                     edges, ew0, ew1, ew2, Abuf, Mb_l0, E_,
                                     x, Spart, nrm, dinv);
  k_stageB<<<1024, 256, 0, stream>>>(XWTh, XWTl, Mb_l0, H2h, H2l, bg,
                                     Hh, Hl, Abuf, nrm, dinv);
  k_stageC<<<512, 256, 0, stream>>>(Wth, Wtl, 0, H2h, H2l, tmph, tmpl);
  k_stageD<<<512, 256, 0, stream>>>(tmph, tmpl, H2h, H2l, Abuf);

  // ---- layer 1 ----
  k_stageA<<<1280, 256, 0, stream>>>(H2h, H2l, Wth, Wtl, 1, XWTh, XWTl,
                                     edges, ew0, ew1, ew2, Abuf, Mb_l1, E_,
                                     x, Spart, nrm, dinv);
  k_stageB<<<512, 256, 0, stream>>>(XWTh, XWTl, Mb_l1, Hh, Hl, bg + 768,
                                    nullptr, nullptr, nullptr, nullptr, nullptr);
  k_stageC<<<512, 256, 0, stream>>>(Wth, Wtl, 1, Hh, Hl, tmph, tmpl);
  k_stageD<<<512, 256, 0, stream>>>(tmph, tmpl, Hh, Hl, Abuf);

  k_maps<<<NGRP, 256, 0, stream>>>(Abuf, emf, pmf, out);
}